// Round 6
// baseline (646.656 us; speedup 1.0000x reference)
//
#include <hip/hip_runtime.h>

#define EMBED 512
#define EXPAND 1024
#define PNUM 16
#define NLEN 1024
#define CHW (PNUM * NLEN)  // 16384
#define SLABS 64

typedef unsigned short u16;
typedef unsigned int u32;
typedef __bf16 bf16x8 __attribute__((ext_vector_type(8)));
typedef u16 u16x8 __attribute__((ext_vector_type(8)));
typedef float f32x4 __attribute__((ext_vector_type(4)));

__device__ __forceinline__ u16 f2bf(float f) {
  u32 u = __builtin_bit_cast(u32, f);
  return (u16)((u + 0x7FFFu + ((u >> 16) & 1u)) >> 16);
}
__device__ __forceinline__ float bf2f(u16 h) {
  return __builtin_bit_cast(float, (u32)h << 16);
}
__device__ __forceinline__ void gld16(const u16* g, u16* l) {
  __builtin_amdgcn_global_load_lds((__attribute__((address_space(1))) void*)g,
                                   (__attribute__((address_space(3))) void*)l,
                                   16, 0, 0);
}
__device__ __forceinline__ f32x4 MFMA(bf16x8 a, bf16x8 b, f32x4 c) {
  return __builtin_amdgcn_mfma_f32_16x16x32_bf16(a, b, c, 0, 0, 0);
}

// ---------------- Kernel W: weights fp32 -> bf16 ----------------
__global__ __launch_bounds__(256) void k_convert_w(
    const float* __restrict__ Wqkv, const float* __restrict__ Wout,
    u16* __restrict__ WvB, u16* __restrict__ WoutB) {
  const int NV = EXPAND * EMBED;  // 524288
  int idx = (blockIdx.x * 256 + threadIdx.x) * 4;
  if (idx < NV) {
    float4 v = *(const float4*)(Wqkv + (size_t)(1 + EXPAND) * EMBED + idx);
    uint2 u = make_uint2((u32)f2bf(v.x) | ((u32)f2bf(v.y) << 16),
                         (u32)f2bf(v.z) | ((u32)f2bf(v.w) << 16));
    *(uint2*)(WvB + idx) = u;
  } else {
    int j = idx - NV;
    float4 v = *(const float4*)(Wout + j);
    uint2 u = make_uint2((u32)f2bf(v.x) | ((u32)f2bf(v.y) << 16),
                         (u32)f2bf(v.z) | ((u32)f2bf(v.w) << 16));
    *(uint2*)(WoutB + j) = u;
  }
}

// ---------------- Kernel A: x -> bf16 transposed + query GEMV ---------------
__global__ __launch_bounds__(256) void k_convert_x(
    const float* __restrict__ x, const float* __restrict__ Wqkv,
    float* __restrict__ q, u16* __restrict__ xbT) {
  __shared__ __align__(16) u16 tile[128 * 64];  // 16 KB
  __shared__ float qp[256 * 4];                 // 4 KB
  const int slab = blockIdx.x >> 3, nw = blockIdx.x & 7;
  const int b = slab >> 4, p = slab & 15;
  const int t = threadIdx.x;
  const int c8 = t & 7;   // c-octet index within 64-c chunk
  const int ng = t >> 3;  // n-group (0..31): n = ng*4..+3
  const float* xs = x + (size_t)b * (EMBED * CHW) + (size_t)p * NLEN + nw * 128;
  u16* dst = xbT + (size_t)slab * (NLEN * EMBED) + (size_t)(nw * 128) * EMBED;
  float qa[4] = {0.f, 0.f, 0.f, 0.f};

  for (int cc = 0; cc < 8; ++cc) {
    const int cbase = cc * 64;
    float4 v[8];
#pragma unroll
    for (int k = 0; k < 8; ++k)
      v[k] = *(const float4*)(xs + (size_t)(cbase + c8 * 8 + k) * CHW + ng * 4);
    const float* w0 = Wqkv + cbase + c8 * 8;
#pragma unroll
    for (int k = 0; k < 8; ++k) {
      qa[0] += w0[k] * v[k].x;
      qa[1] += w0[k] * v[k].y;
      qa[2] += w0[k] * v[k].z;
      qa[3] += w0[k] * v[k].w;
    }
#pragma unroll
    for (int j = 0; j < 4; ++j) {
      const int nl = ng * 4 + j;
      float e[8];
#pragma unroll
      for (int k = 0; k < 8; ++k)
        e[k] = (j == 0) ? v[k].x : (j == 1) ? v[k].y : (j == 2) ? v[k].z : v[k].w;
      uint4 pk;
      pk.x = (u32)f2bf(e[0]) | ((u32)f2bf(e[1]) << 16);
      pk.y = (u32)f2bf(e[2]) | ((u32)f2bf(e[3]) << 16);
      pk.z = (u32)f2bf(e[4]) | ((u32)f2bf(e[5]) << 16);
      pk.w = (u32)f2bf(e[6]) | ((u32)f2bf(e[7]) << 16);
      *(uint4*)(tile + nl * 64 + ((c8 ^ (nl & 7)) << 3)) = pk;
    }
    __syncthreads();
#pragma unroll
    for (int m = 0; m < 4; ++m) {
      const int s = m * 256 + t;
      const int nl = s >> 3, ch = s & 7;
      uint4 vv = *(const uint4*)(tile + nl * 64 + ((ch ^ (nl & 7)) << 3));
      *(uint4*)(dst + (size_t)nl * EMBED + cbase + ch * 8) = vv;
    }
    __syncthreads();
  }
  qp[t * 4 + 0] = qa[0];
  qp[t * 4 + 1] = qa[1];
  qp[t * 4 + 2] = qa[2];
  qp[t * 4 + 3] = qa[3];
  __syncthreads();
  if (t < 128) {
    float a = 0.f;
#pragma unroll
    for (int o = 0; o < 8; ++o) a += qp[((((t >> 2) << 3) + o) << 2) + (t & 3)];
    q[(size_t)slab * NLEN + nw * 128 + t] = a;
  }
}

// ---------------- attn1: softmax + partial y over an n-quarter --------------
__global__ __launch_bounds__(256) void k_attn1(
    const float* __restrict__ q, const u16* __restrict__ xbT,
    float* __restrict__ ypart) {
  __shared__ float red[4];
  __shared__ float sm[256];
  __shared__ float yp[4][512];
  const int slab = blockIdx.x >> 2, qr = blockIdx.x & 3;
  const int t = threadIdx.x, w = t >> 6, l = t & 63;
  const float* qrow = q + (size_t)slab * NLEN;

  float4 q4 = ((const float4*)qrow)[t];
  float m = fmaxf(fmaxf(q4.x, q4.y), fmaxf(q4.z, q4.w));
#pragma unroll
  for (int sh = 32; sh; sh >>= 1) m = fmaxf(m, __shfl_xor(m, sh, 64));
  if (l == 0) red[w] = m;
  __syncthreads();
  float gm = fmaxf(fmaxf(red[0], red[1]), fmaxf(red[2], red[3]));
  float s = __expf(q4.x - gm) + __expf(q4.y - gm) + __expf(q4.z - gm) + __expf(q4.w - gm);
#pragma unroll
  for (int sh = 32; sh; sh >>= 1) s += __shfl_xor(s, sh, 64);
  __syncthreads();
  if (l == 0) red[w] = s;
  __syncthreads();
  float gs = red[0] + red[1] + red[2] + red[3];
  sm[t] = __expf(qrow[qr * 256 + t] - gm) / gs;
  __syncthreads();

  float ya[8] = {0.f, 0.f, 0.f, 0.f, 0.f, 0.f, 0.f, 0.f};
  const u16* xs = xbT + (size_t)slab * (NLEN * EMBED) + (size_t)qr * 256 * EMBED;
  for (int ni = 0; ni < 64; ++ni) {
    const int nloc = ni * 4 + w;
    const float sc = sm[nloc];
    u16x8 v = *(const u16x8*)(xs + (size_t)nloc * EMBED + l * 8);
#pragma unroll
    for (int j = 0; j < 8; ++j) ya[j] += sc * bf2f(v[j]);
  }
#pragma unroll
  for (int j = 0; j < 8; ++j) yp[w][l * 8 + j] = ya[j];
  __syncthreads();
  for (int c = t; c < 512; c += 256)
    ypart[((size_t)slab * 4 + qr) * 512 + c] = yp[0][c] + yp[1][c] + yp[2][c] + yp[3][c];
}

// ---------------- attn2: cv[e] = Wk[e]·y + bk[e] ----------------------------
__global__ __launch_bounds__(256) void k_attn2(
    const float* __restrict__ ypart, const float* __restrict__ Wqkv,
    const float* __restrict__ bqkv, float* __restrict__ cv) {
  __shared__ float yl[512];
  const int slab = blockIdx.x >> 2, ec = blockIdx.x & 3;
  const int t = threadIdx.x;
  const int e = ec * 256 + t;
  const float* yb = ypart + (size_t)slab * 4 * 512;
  for (int c = t; c < 512; c += 256)
    yl[c] = yb[c] + yb[512 + c] + yb[1024 + c] + yb[1536 + c];
  __syncthreads();
  const float* wk = Wqkv + (size_t)(1 + e) * EMBED;
  float a = 0.f;
#pragma unroll 4
  for (int c0 = 0; c0 < EMBED; c0 += 4) {
    float4 wv = *(const float4*)(wk + c0);
    a += wv.x * yl[c0] + wv.y * yl[c0 + 1] + wv.z * yl[c0 + 2] + wv.w * yl[c0 + 3];
  }
  cv[(size_t)slab * EXPAND + e] = a + bqkv[1 + e];
}

// ---------------- 256x256 GEMM core: 4-phase, 1-phase-lookahead reads -------
// D[256(m),256(n)] = A(256,K) * B(256,K)^T. 8 waves (2m x 4n), per-wave 128x64.
// LDS 128KB = 2 K-tile bufs x (A 32KB | B 32KB), 16B-chunk swizzle ch^(row&7).
// Phase p issues ds_reads for phase p+1's MFMA -> compiler emits counted
// lgkmcnt, reads fly under the MFMA cluster (the m201 overlap mechanism).
// Group t (buf = t&1): P1 rd b1(t) | mfma M0N0;  P2 rd a1(t), stage B(t+2)
// | mfma M0N1;  P3 vmcnt(4) rd b0(t+1) | mfma M1N1;  P4 rd a0(t+1),
// stage A(t+2) | mfma M1N0.  vmcnt(4) leaves B(t+2) in flight, forces
// A(t+1)/B(t+1) complete before their buffer is read (lookahead safety).
template <int K, int NT>
__device__ __forceinline__ void gemm256(const u16* __restrict__ Abase,
                                        const u16* __restrict__ Bbase,
                                        u16* lds, f32x4 (&acc)[8][4]) {
  const int t = threadIdx.x;
  const int w = t >> 6, l = t & 63;
  const int wr = w >> 2, wc = w & 3;
  const int lr = l & 15, lj = l >> 4;
  const int rowA0 = wr * 128 + lr;
  const int rowB0 = wc * 64 + lr;

  auto stage = [&](u16* dstBase, const u16* gBase, int kt) {
#pragma unroll
    for (int i = 0; i < 4; ++i) {
      const int s = i * 512 + t;
      const int row = s >> 3;
      const int pch = s & 7;
      gld16(gBase + (size_t)row * K + kt + ((pch ^ (row & 7)) << 3),
            dstBase + s * 8);
    }
  };
  auto rdA = [&](const u16* bufA, int mi, int kc) -> bf16x8 {
    const int row = rowA0 + mi * 16;
    const int ch = kc * 4 + lj;
    return *(const bf16x8*)(bufA + row * 64 + ((ch ^ (row & 7)) << 3));
  };
  auto rdB = [&](const u16* bufB, int ni, int kc) -> bf16x8 {
    const int row = rowB0 + ni * 16;
    const int ch = kc * 4 + lj;
    return *(const bf16x8*)(bufB + row * 64 + ((ch ^ (row & 7)) << 3));
  };

  u16* bA0 = lds;
  u16* bB0 = lds + 16384;
  u16* bA1 = lds + 32768;
  u16* bB1 = lds + 49152;

  // prologue: stage K0 -> buf0, K1 -> buf1; wait K0; preload a0,b0 of tile 0
  stage(bA0, Abase, 0);
  stage(bB0, Bbase, 0);
  stage(bA1, Abase, 64);
  stage(bB1, Bbase, 64);
  asm volatile("s_waitcnt vmcnt(8)" ::: "memory");
  __builtin_amdgcn_s_barrier();
  __builtin_amdgcn_sched_barrier(0);

  bf16x8 a0[4][2], a1[4][2], b1f[2][2], b0X[2][2], b0Y[2][2];
#pragma unroll
  for (int mi = 0; mi < 4; ++mi)
#pragma unroll
    for (int kc = 0; kc < 2; ++kc) a0[mi][kc] = rdA(bA0, mi, kc);
#pragma unroll
  for (int ni = 0; ni < 2; ++ni)
#pragma unroll
    for (int kc = 0; kc < 2; ++kc) b0X[ni][kc] = rdB(bB0, ni, kc);

  auto group = [&](int kt, u16* bufA, u16* bufB, u16* nbufA, u16* nbufB,
                   bf16x8 (&b0c)[2][2], bf16x8 (&b0n)[2][2]) {
    const bool st = (kt + 2) < NT;
    const bool rd = (kt + 1) < NT;
    const int kt2 = (kt + 2) * 64;

    // ---- P1: read b1(cur); MFMA M0N0
#pragma unroll
    for (int ni = 0; ni < 2; ++ni)
#pragma unroll
      for (int kc = 0; kc < 2; ++kc) b1f[ni][kc] = rdB(bufB, ni + 2, kc);
    __builtin_amdgcn_s_barrier();
    __builtin_amdgcn_sched_barrier(0);
    __builtin_amdgcn_s_setprio(1);
#pragma unroll
    for (int mi = 0; mi < 4; ++mi)
#pragma unroll
      for (int ni = 0; ni < 2; ++ni)
#pragma unroll
        for (int kc = 0; kc < 2; ++kc)
          acc[mi][ni] = MFMA(a0[mi][kc], b0c[ni][kc], acc[mi][ni]);
    __builtin_amdgcn_s_setprio(0);
    __builtin_amdgcn_sched_barrier(0);
    __builtin_amdgcn_s_barrier();
    __builtin_amdgcn_sched_barrier(0);

    // ---- P2: read a1(cur); stage B(t+2); MFMA M0N1
#pragma unroll
    for (int mi = 0; mi < 4; ++mi)
#pragma unroll
      for (int kc = 0; kc < 2; ++kc) a1[mi][kc] = rdA(bufA, mi + 4, kc);
    if (st) stage(bufB, Bbase, kt2);
    __builtin_amdgcn_s_barrier();
    __builtin_amdgcn_sched_barrier(0);
    __builtin_amdgcn_s_setprio(1);
#pragma unroll
    for (int mi = 0; mi < 4; ++mi)
#pragma unroll
      for (int ni = 0; ni < 2; ++ni)
#pragma unroll
        for (int kc = 0; kc < 2; ++kc)
          acc[mi][ni + 2] = MFMA(a0[mi][kc], b1f[ni][kc], acc[mi][ni + 2]);
    __builtin_amdgcn_s_setprio(0);
    __builtin_amdgcn_sched_barrier(0);
    __builtin_amdgcn_s_barrier();
    __builtin_amdgcn_sched_barrier(0);

    // ---- P3: counted boundary wait; read b0(next tile); MFMA M1N1
    if (st)
      asm volatile("s_waitcnt vmcnt(4)" ::: "memory");
    else
      asm volatile("s_waitcnt vmcnt(0)" ::: "memory");
    if (rd) {
#pragma unroll
      for (int ni = 0; ni < 2; ++ni)
#pragma unroll
        for (int kc = 0; kc < 2; ++kc) b0n[ni][kc] = rdB(nbufB, ni, kc);
    }
    __builtin_amdgcn_s_barrier();
    __builtin_amdgcn_sched_barrier(0);
    __builtin_amdgcn_s_setprio(1);
#pragma unroll
    for (int mi = 0; mi < 4; ++mi)
#pragma unroll
      for (int ni = 0; ni < 2; ++ni)
#pragma unroll
        for (int kc = 0; kc < 2; ++kc)
          acc[mi + 4][ni + 2] = MFMA(a1[mi][kc], b1f[ni][kc], acc[mi + 4][ni + 2]);
    __builtin_amdgcn_s_setprio(0);
    __builtin_amdgcn_sched_barrier(0);
    __builtin_amdgcn_s_barrier();
    __builtin_amdgcn_sched_barrier(0);

    // ---- P4: read a0(next tile); stage A(t+2); MFMA M1N0
    if (rd) {
#pragma unroll
      for (int mi = 0; mi < 4; ++mi)
#pragma unroll
        for (int kc = 0; kc < 2; ++kc) a0[mi][kc] = rdA(nbufA, mi, kc);
    }
    if (st) stage(bufA, Abase, kt2);
    __builtin_amdgcn_s_barrier();
    __builtin_amdgcn_sched_barrier(0);
    __builtin_amdgcn_s_setprio(1);
#pragma unroll
    for (int mi = 0; mi < 4; ++mi)
#pragma unroll
      for (int ni = 0; ni < 2; ++ni)
#pragma unroll
        for (int kc = 0; kc < 2; ++kc)
          acc[mi + 4][ni] = MFMA(a1[mi][kc], b0c[ni][kc], acc[mi + 4][ni]);
    __builtin_amdgcn_s_setprio(0);
    __builtin_amdgcn_sched_barrier(0);
    __builtin_amdgcn_s_barrier();
    __builtin_amdgcn_sched_barrier(0);
  };

#pragma unroll 1
  for (int kt = 0; kt < NT; kt += 2) {
    group(kt, bA0, bB0, bA1, bB1, b0X, b0Y);
    group(kt + 1, bA1, bB1, bA0, bB0, b0Y, b0X);
  }
}

// ---------------- GEMM1: midT[n][e] = relu(valT + bv)*cv, bf16 --------------
__global__ __launch_bounds__(512, 2) void k_gemm1(
    const u16* __restrict__ xbT, const u16* __restrict__ WvB,
    const float* __restrict__ bqkv, const float* __restrict__ cv,
    u16* __restrict__ midT) {
  __shared__ __align__(16) u16 lds[65536];  // 128 KB
  const int bid = blockIdx.x;
  const int xc = bid & 7, k = bid >> 3;
  const int te = k & 3;
  const int gg = ((k >> 2) << 3) | xc;  // 0..255
  const int slab = gg >> 2, tn = gg & 3;
  const u16* A = xbT + (size_t)slab * (NLEN * EMBED) + (size_t)tn * 256 * EMBED;
  const u16* B = WvB + (size_t)te * 256 * EMBED;
  f32x4 acc[8][4];
  const f32x4 z = {0.f, 0.f, 0.f, 0.f};
#pragma unroll
  for (int i = 0; i < 8; ++i)
#pragma unroll
    for (int j = 0; j < 4; ++j) acc[i][j] = z;
  gemm256<EMBED, 8>(A, B, lds, acc);

  const int t = threadIdx.x, w = t >> 6, l = t & 63;
  const int wr = w >> 2, wc = w & 3;
  const int lr = l & 15, lq4 = (l >> 4) * 4;
#pragma unroll
  for (int ni = 0; ni < 4; ++ni) {
    const int col = wc * 64 + ni * 16 + lr;
    const int e = te * 256 + col;
    const float bv = bqkv[1 + EXPAND + e];
    const float cve = cv[(size_t)slab * EXPAND + e];
#pragma unroll
    for (int mi = 0; mi < 8; ++mi) {
      const int nr = wr * 128 + mi * 16 + lq4;
#pragma unroll
      for (int r = 0; r < 4; ++r) {
        float v = acc[mi][ni][r] + bv;
        v = v > 0.f ? v * cve : 0.f;
        const int row = nr + r;
        lds[row * 256 + ((((col >> 3) ^ (row & 7)) << 3) | (col & 7))] = f2bf(v);
      }
    }
  }
  __syncthreads();
  u16* mt = midT + (size_t)slab * (NLEN * EXPAND) + (size_t)te * 256;
#pragma unroll
  for (int it = 0; it < 16; ++it) {
    const int row = w * 32 + it * 2 + (l >> 5);
    const int ch = (l & 31) ^ (row & 7);
    uint4 v = *(const uint4*)(lds + row * 256 + ch * 8);
    *(uint4*)(mt + (size_t)(tn * 256 + row) * EXPAND + (l & 31) * 8) = v;
  }
}

// ---------------- GEMM2: out = Wout*mid + bout ------------------------------
__global__ __launch_bounds__(512, 2) void k_gemm2(
    const u16* __restrict__ midT, const u16* __restrict__ WoutB,
    const float* __restrict__ bout, float* __restrict__ out) {
  __shared__ __align__(16) u16 lds[65536];  // 128 KB
  const int bid = blockIdx.x;
  const int xc = bid & 7, k = bid >> 3;
  const int to = k & 1;
  const int gg = ((k >> 1) << 3) | xc;  // 0..255
  const int slab = gg >> 2, tn = gg & 3;
  const int b = slab >> 4, p = slab & 15;
  const u16* A = midT + (size_t)slab * (NLEN * EXPAND) + (size_t)tn * 256 * EXPAND;
  const u16* B = WoutB + (size_t)to * 256 * EXPAND;
  f32x4 acc[8][4];
  const f32x4 z = {0.f, 0.f, 0.f, 0.f};
#pragma unroll
  for (int i = 0; i < 8; ++i)
#pragma unroll
    for (int j = 0; j < 4; ++j) acc[i][j] = z;
  gemm256<EXPAND, 16>(A, B, lds, acc);

  const int t = threadIdx.x, w = t >> 6, l = t & 63;
  const int wr = w >> 2, wc = w & 3;
  const int lr = l & 15, lq4 = (l >> 4) * 4;
  float* ob = out + (size_t)b * (EMBED * CHW) + (size_t)p * NLEN;
#pragma unroll
  for (int ni = 0; ni < 4; ++ni) {
    const int o = to * 256 + wc * 64 + ni * 16 + lr;
    const float bo = bout[o];
#pragma unroll
    for (int mi = 0; mi < 8; ++mi) {
      const int nr = tn * 256 + wr * 128 + mi * 16 + lq4;
      float4 v;
      v.x = acc[mi][ni][0] + bo;
      v.y = acc[mi][ni][1] + bo;
      v.z = acc[mi][ni][2] + bo;
      v.w = acc[mi][ni][3] + bo;
      *(float4*)(ob + (size_t)o * CHW + nr) = v;
    }
  }
}

extern "C" void kernel_launch(void* const* d_in, const int* in_sizes, int n_in,
                              void* d_out, int out_size, void* d_ws, size_t ws_size,
                              hipStream_t stream) {
  const float* x = (const float*)d_in[0];
  const float* Wqkv = (const float*)d_in[1];
  const float* bqkv = (const float*)d_in[2];
  const float* Wout = (const float*)d_in[3];
  const float* bout = (const float*)d_in[4];
  float* out = (float*)d_out;

  char* ws = (char*)d_ws;
  u16* xbT = (u16*)ws;                  // 67108864 B
  u16* WvB = (u16*)(ws + 67108864);     // 1048576 B
  u16* WoutB = (u16*)(ws + 68157440);   // 1048576 B
  float* q = (float*)(ws + 69206016);   // 262144 B
  float* cv = (float*)(ws + 69468160);  // 262144 B
  u16* midT = (u16*)(ws + 69730304);    // 134217728 B
  float* ypart = (float*)(ws + 69730304);  // aliases midT head (attn2 before gemm1)

  k_convert_w<<<1024, 256, 0, stream>>>(Wqkv, Wout, WvB, WoutB);
  k_convert_x<<<512, 256, 0, stream>>>(x, Wqkv, q, xbT);
  k_attn1<<<256, 256, 0, stream>>>(q, xbT, ypart);
  k_attn2<<<256, 256, 0, stream>>>(ypart, Wqkv, bqkv, cv);
  k_gemm1<<<1024, 512, 0, stream>>>(xbT, WvB, bqkv, cv, midT);
  k_gemm2<<<512, 512, 0, stream>>>(midT, WoutB, bout, out);
}

// Round 7
// 267.194 us; speedup vs baseline: 2.4202x; 2.4202x over previous
//
#include <hip/hip_runtime.h>

#define EMBED 512
#define EXPAND 1024
#define PNUM 16
#define NLEN 1024
#define CHW (PNUM * NLEN)  // 16384
#define SLABS 64

typedef unsigned short u16;
typedef unsigned int u32;
typedef __bf16 bf16x8 __attribute__((ext_vector_type(8)));
typedef u16 u16x8 __attribute__((ext_vector_type(8)));
typedef float f32x4 __attribute__((ext_vector_type(4)));

__device__ __forceinline__ u16 f2bf(float f) {
  u32 u = __builtin_bit_cast(u32, f);
  return (u16)((u + 0x7FFFu + ((u >> 16) & 1u)) >> 16);
}
__device__ __forceinline__ float bf2f(u16 h) {
  return __builtin_bit_cast(float, (u32)h << 16);
}
__device__ __forceinline__ void gld16(const u16* g, u16* l) {
  __builtin_amdgcn_global_load_lds((__attribute__((address_space(1))) void*)g,
                                   (__attribute__((address_space(3))) void*)l,
                                   16, 0, 0);
}
__device__ __forceinline__ f32x4 MFMA(bf16x8 a, bf16x8 b, f32x4 c) {
  return __builtin_amdgcn_mfma_f32_16x16x32_bf16(a, b, c, 0, 0, 0);
}

// ---------------- Kernel W: weights fp32 -> bf16 ----------------
__global__ __launch_bounds__(256) void k_convert_w(
    const float* __restrict__ Wqkv, const float* __restrict__ Wout,
    u16* __restrict__ WvB, u16* __restrict__ WoutB) {
  const int NV = EXPAND * EMBED;  // 524288
  int idx = (blockIdx.x * 256 + threadIdx.x) * 4;
  if (idx < NV) {
    float4 v = *(const float4*)(Wqkv + (size_t)(1 + EXPAND) * EMBED + idx);
    uint2 u = make_uint2((u32)f2bf(v.x) | ((u32)f2bf(v.y) << 16),
                         (u32)f2bf(v.z) | ((u32)f2bf(v.w) << 16));
    *(uint2*)(WvB + idx) = u;
  } else {
    int j = idx - NV;
    float4 v = *(const float4*)(Wout + j);
    uint2 u = make_uint2((u32)f2bf(v.x) | ((u32)f2bf(v.y) << 16),
                         (u32)f2bf(v.z) | ((u32)f2bf(v.w) << 16));
    *(uint2*)(WoutB + j) = u;
  }
}

// ---------------- Kernel A: x -> bf16 transposed + query GEMV ---------------
__global__ __launch_bounds__(256) void k_convert_x(
    const float* __restrict__ x, const float* __restrict__ Wqkv,
    float* __restrict__ q, u16* __restrict__ xbT) {
  __shared__ __align__(16) u16 tile[128 * 64];  // 16 KB
  __shared__ float qp[256 * 4];                 // 4 KB
  const int slab = blockIdx.x >> 3, nw = blockIdx.x & 7;
  const int b = slab >> 4, p = slab & 15;
  const int t = threadIdx.x;
  const int c8 = t & 7;   // c-octet index within 64-c chunk
  const int ng = t >> 3;  // n-group (0..31): n = ng*4..+3
  const float* xs = x + (size_t)b * (EMBED * CHW) + (size_t)p * NLEN + nw * 128;
  u16* dst = xbT + (size_t)slab * (NLEN * EMBED) + (size_t)(nw * 128) * EMBED;
  float qa[4] = {0.f, 0.f, 0.f, 0.f};

  for (int cc = 0; cc < 8; ++cc) {
    const int cbase = cc * 64;
    float4 v[8];
#pragma unroll
    for (int k = 0; k < 8; ++k)
      v[k] = *(const float4*)(xs + (size_t)(cbase + c8 * 8 + k) * CHW + ng * 4);
    const float* w0 = Wqkv + cbase + c8 * 8;
#pragma unroll
    for (int k = 0; k < 8; ++k) {
      qa[0] += w0[k] * v[k].x;
      qa[1] += w0[k] * v[k].y;
      qa[2] += w0[k] * v[k].z;
      qa[3] += w0[k] * v[k].w;
    }
#pragma unroll
    for (int j = 0; j < 4; ++j) {
      const int nl = ng * 4 + j;
      float e[8];
#pragma unroll
      for (int k = 0; k < 8; ++k)
        e[k] = (j == 0) ? v[k].x : (j == 1) ? v[k].y : (j == 2) ? v[k].z : v[k].w;
      uint4 pk;
      pk.x = (u32)f2bf(e[0]) | ((u32)f2bf(e[1]) << 16);
      pk.y = (u32)f2bf(e[2]) | ((u32)f2bf(e[3]) << 16);
      pk.z = (u32)f2bf(e[4]) | ((u32)f2bf(e[5]) << 16);
      pk.w = (u32)f2bf(e[6]) | ((u32)f2bf(e[7]) << 16);
      *(uint4*)(tile + nl * 64 + ((c8 ^ (nl & 7)) << 3)) = pk;
    }
    __syncthreads();
#pragma unroll
    for (int m = 0; m < 4; ++m) {
      const int s = m * 256 + t;
      const int nl = s >> 3, ch = s & 7;
      uint4 vv = *(const uint4*)(tile + nl * 64 + ((ch ^ (nl & 7)) << 3));
      *(uint4*)(dst + (size_t)nl * EMBED + cbase + ch * 8) = vv;
    }
    __syncthreads();
  }
  qp[t * 4 + 0] = qa[0];
  qp[t * 4 + 1] = qa[1];
  qp[t * 4 + 2] = qa[2];
  qp[t * 4 + 3] = qa[3];
  __syncthreads();
  if (t < 128) {
    float a = 0.f;
#pragma unroll
    for (int o = 0; o < 8; ++o) a += qp[((((t >> 2) << 3) + o) << 2) + (t & 3)];
    q[(size_t)slab * NLEN + nw * 128 + t] = a;
  }
}

// ---------------- attn1: softmax + partial y over an n-quarter --------------
__global__ __launch_bounds__(256) void k_attn1(
    const float* __restrict__ q, const u16* __restrict__ xbT,
    float* __restrict__ ypart) {
  __shared__ float red[4];
  __shared__ float sm[256];
  __shared__ float yp[4][512];
  const int slab = blockIdx.x >> 2, qr = blockIdx.x & 3;
  const int t = threadIdx.x, w = t >> 6, l = t & 63;
  const float* qrow = q + (size_t)slab * NLEN;

  float4 q4 = ((const float4*)qrow)[t];
  float m = fmaxf(fmaxf(q4.x, q4.y), fmaxf(q4.z, q4.w));
#pragma unroll
  for (int sh = 32; sh; sh >>= 1) m = fmaxf(m, __shfl_xor(m, sh, 64));
  if (l == 0) red[w] = m;
  __syncthreads();
  float gm = fmaxf(fmaxf(red[0], red[1]), fmaxf(red[2], red[3]));
  float s = __expf(q4.x - gm) + __expf(q4.y - gm) + __expf(q4.z - gm) + __expf(q4.w - gm);
#pragma unroll
  for (int sh = 32; sh; sh >>= 1) s += __shfl_xor(s, sh, 64);
  __syncthreads();
  if (l == 0) red[w] = s;
  __syncthreads();
  float gs = red[0] + red[1] + red[2] + red[3];
  sm[t] = __expf(qrow[qr * 256 + t] - gm) / gs;
  __syncthreads();

  float ya[8] = {0.f, 0.f, 0.f, 0.f, 0.f, 0.f, 0.f, 0.f};
  const u16* xs = xbT + (size_t)slab * (NLEN * EMBED) + (size_t)qr * 256 * EMBED;
  for (int ni = 0; ni < 64; ++ni) {
    const int nloc = ni * 4 + w;
    const float sc = sm[nloc];
    u16x8 v = *(const u16x8*)(xs + (size_t)nloc * EMBED + l * 8);
#pragma unroll
    for (int j = 0; j < 8; ++j) ya[j] += sc * bf2f(v[j]);
  }
#pragma unroll
  for (int j = 0; j < 8; ++j) yp[w][l * 8 + j] = ya[j];
  __syncthreads();
  for (int c = t; c < 512; c += 256)
    ypart[((size_t)slab * 4 + qr) * 512 + c] = yp[0][c] + yp[1][c] + yp[2][c] + yp[3][c];
}

// ---------------- attn2: cv[e] = Wk[e]·y + bk[e] ----------------------------
__global__ __launch_bounds__(256) void k_attn2(
    const float* __restrict__ ypart, const float* __restrict__ Wqkv,
    const float* __restrict__ bqkv, float* __restrict__ cv) {
  __shared__ float yl[512];
  const int slab = blockIdx.x >> 2, ec = blockIdx.x & 3;
  const int t = threadIdx.x;
  const int e = ec * 256 + t;
  const float* yb = ypart + (size_t)slab * 4 * 512;
  for (int c = t; c < 512; c += 256)
    yl[c] = yb[c] + yb[512 + c] + yb[1024 + c] + yb[1536 + c];
  __syncthreads();
  const float* wk = Wqkv + (size_t)(1 + e) * EMBED;
  float a = 0.f;
#pragma unroll 4
  for (int c0 = 0; c0 < EMBED; c0 += 4) {
    float4 wv = *(const float4*)(wk + c0);
    a += wv.x * yl[c0] + wv.y * yl[c0 + 1] + wv.z * yl[c0 + 2] + wv.w * yl[c0 + 3];
  }
  cv[(size_t)slab * EXPAND + e] = a + bqkv[1 + e];
}

// ---------------- 256x256 GEMM core: 4-phase, spread staging, vmcnt(6) ------
// D[256(m),256(n)] = A(256,K)*B(256,K)^T. 8 waves (2m x 4n), per-wave 128x64.
// LDS 128KB = 2 K-tile bufs x (A 32KB | B 32KB), 16B-chunk swizzle ch^(row&7).
// Staging: 1 half-tile (2 gld16/thread) per phase (m201 cadence):
//   ph0: Aq13(t+1) [rows 64-127,192-255 of other buf; free since t-1 ph2]
//   ph1: Aq02(t+2) [this buf; a0 reads drained at ph0 MFMA]
//   ph2: Bh0(t+2)  [B reads all drained by end ph1]
//   ph3: Bh1(t+2)
// Boundary: vmcnt(6) leaves t+2's 3 half-tiles in flight, forces Aq13(t+1)
// and all tile-(t+1) data complete. Tail: vmcnt(0).
template <int K, int NT>
__device__ __forceinline__ void gemm256(const u16* __restrict__ Abase,
                                        const u16* __restrict__ Bbase,
                                        u16* lds, f32x4 (&acc)[8][4]) {
  const int t = threadIdx.x;
  const int w = t >> 6, l = t & 63;
  const int wr = w >> 2, wc = w & 3;
  const int lr = l & 15, lj = l >> 4;
  const int rowA0 = wr * 128 + lr;
  const int rowB0 = wc * 64 + lr;

  // one half-tile = two 8KB passes at u16x8-chunk offsets s0, s1
  auto stage2 = [&](u16* dstBase, const u16* gBase, int kt, int s0, int s1) {
    {
      const int s = s0 + t;
      const int row = s >> 3, pch = s & 7;
      gld16(gBase + (size_t)row * K + kt + ((pch ^ (row & 7)) << 3),
            dstBase + s * 8);
    }
    {
      const int s = s1 + t;
      const int row = s >> 3, pch = s & 7;
      gld16(gBase + (size_t)row * K + kt + ((pch ^ (row & 7)) << 3),
            dstBase + s * 8);
    }
  };
  auto rdA = [&](const u16* bufA, int mi, int kc) -> bf16x8 {
    const int row = rowA0 + mi * 16;
    const int ch = kc * 4 + lj;
    return *(const bf16x8*)(bufA + row * 64 + ((ch ^ (row & 7)) << 3));
  };
  auto rdB = [&](const u16* bufB, int ni, int kc) -> bf16x8 {
    const int row = rowB0 + ni * 16;
    const int ch = kc * 4 + lj;
    return *(const bf16x8*)(bufB + row * 64 + ((ch ^ (row & 7)) << 3));
  };

  u16* bA0 = lds;
  u16* bB0 = lds + 16384;
  u16* bA1 = lds + 32768;
  u16* bB1 = lds + 49152;

  // prologue: tile0 full (4 half-tiles) + tile1 {Aq02,Bh0,Bh1}; vmcnt(6)
  stage2(bA0, Abase, 0, 0, 1024);     // Aq02(0)
  stage2(bB0, Bbase, 0, 0, 512);      // Bh0(0)
  stage2(bB0, Bbase, 0, 1024, 1536);  // Bh1(0)
  stage2(bA0, Abase, 0, 512, 1536);   // Aq13(0)
  stage2(bA1, Abase, 64, 0, 1024);    // Aq02(1)
  stage2(bB1, Bbase, 64, 0, 512);     // Bh0(1)
  stage2(bB1, Bbase, 64, 1024, 1536); // Bh1(1)
  asm volatile("s_waitcnt vmcnt(6)" ::: "memory");  // tile0 fully landed
  __builtin_amdgcn_s_barrier();
  __builtin_amdgcn_sched_barrier(0);

#pragma unroll 1
  for (int kt = 0; kt < NT; ++kt) {
    u16* bufA = lds + (kt & 1) * 32768;
    u16* bufB = bufA + 16384;
    u16* nbufA = lds + (((kt + 1) & 1)) * 32768;
    const bool st1 = (kt + 1) < NT;
    const bool st2 = (kt + 2) < NT;
    const int k1 = (kt + 1) * 64, k2 = (kt + 2) * 64;
    bf16x8 a0[4][2], a1[4][2], b0[2][2], b1[2][2];

    // ---- ph0: rd a0(8)+b0(4); stage Aq13(t+1); mfma M0N0
#pragma unroll
    for (int mi = 0; mi < 4; ++mi)
#pragma unroll
      for (int kc = 0; kc < 2; ++kc) a0[mi][kc] = rdA(bufA, mi, kc);
#pragma unroll
    for (int ni = 0; ni < 2; ++ni)
#pragma unroll
      for (int kc = 0; kc < 2; ++kc) b0[ni][kc] = rdB(bufB, ni, kc);
    if (st1) stage2(nbufA, Abase, k1, 512, 1536);
    __builtin_amdgcn_s_barrier();
    __builtin_amdgcn_sched_barrier(0);
    __builtin_amdgcn_s_setprio(1);
#pragma unroll
    for (int mi = 0; mi < 4; ++mi)
#pragma unroll
      for (int ni = 0; ni < 2; ++ni)
#pragma unroll
        for (int kc = 0; kc < 2; ++kc)
          acc[mi][ni] = MFMA(a0[mi][kc], b0[ni][kc], acc[mi][ni]);
    __builtin_amdgcn_s_setprio(0);
    __builtin_amdgcn_sched_barrier(0);
    __builtin_amdgcn_s_barrier();
    __builtin_amdgcn_sched_barrier(0);

    // ---- ph1: rd b1(4); stage Aq02(t+2); mfma M0N1
#pragma unroll
    for (int ni = 0; ni < 2; ++ni)
#pragma unroll
      for (int kc = 0; kc < 2; ++kc) b1[ni][kc] = rdB(bufB, ni + 2, kc);
    if (st2) stage2(bufA, Abase, k2, 0, 1024);
    __builtin_amdgcn_s_barrier();
    __builtin_amdgcn_sched_barrier(0);
    __builtin_amdgcn_s_setprio(1);
#pragma unroll
    for (int mi = 0; mi < 4; ++mi)
#pragma unroll
      for (int ni = 0; ni < 2; ++ni)
#pragma unroll
        for (int kc = 0; kc < 2; ++kc)
          acc[mi][ni + 2] = MFMA(a0[mi][kc], b1[ni][kc], acc[mi][ni + 2]);
    __builtin_amdgcn_s_setprio(0);
    __builtin_amdgcn_sched_barrier(0);
    __builtin_amdgcn_s_barrier();
    __builtin_amdgcn_sched_barrier(0);

    // ---- ph2: rd a1(8); stage Bh0(t+2); mfma M1N1
#pragma unroll
    for (int mi = 0; mi < 4; ++mi)
#pragma unroll
      for (int kc = 0; kc < 2; ++kc) a1[mi][kc] = rdA(bufA, mi + 4, kc);
    if (st2) stage2(bufB, Bbase, k2, 0, 512);
    __builtin_amdgcn_s_barrier();
    __builtin_amdgcn_sched_barrier(0);
    __builtin_amdgcn_s_setprio(1);
#pragma unroll
    for (int mi = 0; mi < 4; ++mi)
#pragma unroll
      for (int ni = 0; ni < 2; ++ni)
#pragma unroll
        for (int kc = 0; kc < 2; ++kc)
          acc[mi + 4][ni + 2] = MFMA(a1[mi][kc], b1[ni][kc], acc[mi + 4][ni + 2]);
    __builtin_amdgcn_s_setprio(0);
    __builtin_amdgcn_sched_barrier(0);
    __builtin_amdgcn_s_barrier();
    __builtin_amdgcn_sched_barrier(0);

    // ---- ph3: stage Bh1(t+2); mfma M1N0; counted boundary wait
    if (st2) stage2(bufB, Bbase, k2, 1024, 1536);
    __builtin_amdgcn_s_barrier();
    __builtin_amdgcn_sched_barrier(0);
    __builtin_amdgcn_s_setprio(1);
#pragma unroll
    for (int mi = 0; mi < 4; ++mi)
#pragma unroll
      for (int ni = 0; ni < 2; ++ni)
#pragma unroll
        for (int kc = 0; kc < 2; ++kc)
          acc[mi + 4][ni] = MFMA(a1[mi][kc], b0[ni][kc], acc[mi + 4][ni]);
    __builtin_amdgcn_s_setprio(0);
    __builtin_amdgcn_sched_barrier(0);
    if (st2)
      asm volatile("s_waitcnt vmcnt(6)" ::: "memory");
    else
      asm volatile("s_waitcnt vmcnt(0)" ::: "memory");
    __builtin_amdgcn_s_barrier();
    __builtin_amdgcn_sched_barrier(0);
  }
}

// ---------------- GEMM1: midT[n][e] = relu(valT + bv)*cv, bf16 --------------
__global__ __launch_bounds__(512, 2) void k_gemm1(
    const u16* __restrict__ xbT, const u16* __restrict__ WvB,
    const float* __restrict__ bqkv, const float* __restrict__ cv,
    u16* __restrict__ midT) {
  __shared__ __align__(16) u16 lds[65536];  // 128 KB
  const int bid = blockIdx.x;
  const int xc = bid & 7, k = bid >> 3;
  const int te = k & 3;
  const int gg = ((k >> 2) << 3) | xc;  // 0..255
  const int slab = gg >> 2, tn = gg & 3;
  const u16* A = xbT + (size_t)slab * (NLEN * EMBED) + (size_t)tn * 256 * EMBED;
  const u16* B = WvB + (size_t)te * 256 * EMBED;
  f32x4 acc[8][4];
  const f32x4 z = {0.f, 0.f, 0.f, 0.f};
#pragma unroll
  for (int i = 0; i < 8; ++i)
#pragma unroll
    for (int j = 0; j < 4; ++j) acc[i][j] = z;
  gemm256<EMBED, 8>(A, B, lds, acc);

  const int t = threadIdx.x, w = t >> 6, l = t & 63;
  const int wr = w >> 2, wc = w & 3;
  const int lr = l & 15, lq4 = (l >> 4) * 4;
#pragma unroll
  for (int ni = 0; ni < 4; ++ni) {
    const int col = wc * 64 + ni * 16 + lr;
    const int e = te * 256 + col;
    const float bv = bqkv[1 + EXPAND + e];
    const float cve = cv[(size_t)slab * EXPAND + e];
#pragma unroll
    for (int mi = 0; mi < 8; ++mi) {
      const int nr = wr * 128 + mi * 16 + lq4;
#pragma unroll
      for (int r = 0; r < 4; ++r) {
        float v = acc[mi][ni][r] + bv;
        v = v > 0.f ? v * cve : 0.f;
        const int row = nr + r;
        lds[row * 256 + ((((col >> 3) ^ (row & 7)) << 3) | (col & 7))] = f2bf(v);
      }
    }
  }
  __syncthreads();
  u16* mt = midT + (size_t)slab * (NLEN * EXPAND) + (size_t)te * 256;
#pragma unroll
  for (int it = 0; it < 16; ++it) {
    const int row = w * 32 + it * 2 + (l >> 5);
    const int ch = (l & 31) ^ (row & 7);
    uint4 v = *(const uint4*)(lds + row * 256 + ch * 8);
    *(uint4*)(mt + (size_t)(tn * 256 + row) * EXPAND + (l & 31) * 8) = v;
  }
}

// ---------------- GEMM2: out = Wout*mid + bout ------------------------------
__global__ __launch_bounds__(512, 2) void k_gemm2(
    const u16* __restrict__ midT, const u16* __restrict__ WoutB,
    const float* __restrict__ bout, float* __restrict__ out) {
  __shared__ __align__(16) u16 lds[65536];  // 128 KB
  const int bid = blockIdx.x;
  const int xc = bid & 7, k = bid >> 3;
  const int to = k & 1;
  const int gg = ((k >> 1) << 3) | xc;  // 0..255
  const int slab = gg >> 2, tn = gg & 3;
  const int b = slab >> 4, p = slab & 15;
  const u16* A = midT + (size_t)slab * (NLEN * EXPAND) + (size_t)tn * 256 * EXPAND;
  const u16* B = WoutB + (size_t)to * 256 * EXPAND;
  f32x4 acc[8][4];
  const f32x4 z = {0.f, 0.f, 0.f, 0.f};
#pragma unroll
  for (int i = 0; i < 8; ++i)
#pragma unroll
    for (int j = 0; j < 4; ++j) acc[i][j] = z;
  gemm256<EXPAND, 16>(A, B, lds, acc);

  const int t = threadIdx.x, w = t >> 6, l = t & 63;
  const int wr = w >> 2, wc = w & 3;
  const int lr = l & 15, lq4 = (l >> 4) * 4;
  float* ob = out + (size_t)b * (EMBED * CHW) + (size_t)p * NLEN;
#pragma unroll
  for (int ni = 0; ni < 4; ++ni) {
    const int o = to * 256 + wc * 64 + ni * 16 + lr;
    const float bo = bout[o];
#pragma unroll
    for (int mi = 0; mi < 8; ++mi) {
      const int nr = tn * 256 + wr * 128 + mi * 16 + lq4;
      float4 v;
      v.x = acc[mi][ni][0] + bo;
      v.y = acc[mi][ni][1] + bo;
      v.z = acc[mi][ni][2] + bo;
      v.w = acc[mi][ni][3] + bo;
      *(float4*)(ob + (size_t)o * CHW + nr) = v;
    }
  }
}

extern "C" void kernel_launch(void* const* d_in, const int* in_sizes, int n_in,
                              void* d_out, int out_size, void* d_ws, size_t ws_size,
                              hipStream_t stream) {
  const float* x = (const float*)d_in[0];
  const float* Wqkv = (const float*)d_in[1];
  const float* bqkv = (const float*)d_in[2];
  const float* Wout = (const float*)d_in[3];
  const float* bout = (const float*)d_in[4];
  float* out = (float*)d_out;

  char* ws = (char*)d_ws;
  u16* xbT = (u16*)ws;                  // 67108864 B
  u16* WvB = (u16*)(ws + 67108864);     // 1048576 B
  u16* WoutB = (u16*)(ws + 68157440);   // 1048576 B
  float* q = (float*)(ws + 69206016);   // 262144 B
  float* cv = (float*)(ws + 69468160);  // 262144 B
  u16* midT = (u16*)(ws + 69730304);    // 134217728 B
  float* ypart = (float*)(ws + 69730304);  // aliases midT head (attn2 before gemm1)

  k_convert_w<<<1024, 256, 0, stream>>>(Wqkv, Wout, WvB, WoutB);
  k_convert_x<<<512, 256, 0, stream>>>(x, Wqkv, q, xbT);
  k_attn1<<<256, 256, 0, stream>>>(q, xbT, ypart);
  k_attn2<<<256, 256, 0, stream>>>(ypart, Wqkv, bqkv, cv);
  k_gemm1<<<1024, 512, 0, stream>>>(xbT, WvB, bqkv, cv, midT);
  k_gemm2<<<512, 512, 0, stream>>>(midT, WoutB, bout, out);
}